// Round 1
// 752.636 us; speedup vs baseline: 1.1001x; 1.1001x over previous
//
#include <hip/hip_runtime.h>
#include <math.h>

// Problem constants (fixed shapes from setup_inputs)
#define Bn 32
#define TT 512
#define TM 2048
#define DD 512
#define MMp 80
#define NEGF (-1.0e9f)

// d_out layout: [h_expanded 32*2048*512][dur_loss 1][durations 32*512], all float32
constexpr size_t LOSS_OFF = (size_t)Bn * TM * DD;          // 33554432
constexpr size_t DUR_OFF  = LOSS_OFF + 1;                  // 33554433

// ---------------------------------------------------------------------------
// K0: build wTx[96][512]: rows 0..79 = w_proj^T, row 80 = b_proj, 81..95 = 0
// ---------------------------------------------------------------------------
__global__ __launch_bounds__(256) void k0_wtx(const float* __restrict__ w,
                                              const float* __restrict__ bias,
                                              float* __restrict__ wTx) {
    int m = blockIdx.x;
    for (int d = threadIdx.x; d < DD; d += 256) {
        float v = 0.f;
        if (m < 80) v = w[d * 80 + m];
        else if (m == 80) v = bias[d];
        wTx[m * DD + d] = v;
    }
}

// ---------------------------------------------------------------------------
// K1: hwX[b][m][i] = sum_d h_text[b][i][d] * wTx[m][d]   (m<96, row80 = h.b)
// ---------------------------------------------------------------------------
__global__ __launch_bounds__(256) void k1_hw(const float* __restrict__ h_text,
                                             const float* __restrict__ wTx,
                                             float* __restrict__ hwX) {
    int bid = blockIdx.x;
    int b = bid >> 3;
    int i0 = (bid & 7) * 64;
    int t = threadIdx.x;
    int tr = t & 15, tc = t >> 4;
    __shared__ __align__(16) float Asub[64 * 68];
    __shared__ __align__(16) float Bsub[96 * 68];
    float acc[4][6];
#pragma unroll
    for (int a = 0; a < 4; ++a)
#pragma unroll
        for (int c = 0; c < 6; ++c) acc[a][c] = 0.f;

    for (int d0 = 0; d0 < DD; d0 += 64) {
        __syncthreads();
#pragma unroll
        for (int p = 0; p < 4; ++p) {
            int lin = p * 256 + t;              // 0..1023
            int r = lin >> 4, dq = lin & 15;
            *(float4*)&Asub[r * 68 + dq * 4] =
                *(const float4*)&h_text[((size_t)(b * TT + i0 + r)) * DD + d0 + dq * 4];
        }
#pragma unroll
        for (int p = 0; p < 6; ++p) {
            int lin = p * 256 + t;              // 0..1535
            int cc = lin >> 4, dq = lin & 15;
            *(float4*)&Bsub[cc * 68 + dq * 4] =
                *(const float4*)&wTx[(size_t)cc * DD + d0 + dq * 4];
        }
        __syncthreads();
#pragma unroll
        for (int dd = 0; dd < 16; ++dd) {
            float4 a[4], bb[6];
#pragma unroll
            for (int ri = 0; ri < 4; ++ri)
                a[ri] = *(const float4*)&Asub[(tr * 4 + ri) * 68 + dd * 4];
#pragma unroll
            for (int ci = 0; ci < 6; ++ci)
                bb[ci] = *(const float4*)&Bsub[(tc * 6 + ci) * 68 + dd * 4];
#pragma unroll
            for (int ri = 0; ri < 4; ++ri)
#pragma unroll
                for (int ci = 0; ci < 6; ++ci) {
                    acc[ri][ci] += a[ri].x * bb[ci].x;
                    acc[ri][ci] += a[ri].y * bb[ci].y;
                    acc[ri][ci] += a[ri].z * bb[ci].z;
                    acc[ri][ci] += a[ri].w * bb[ci].w;
                }
        }
    }
#pragma unroll
    for (int ri = 0; ri < 4; ++ri)
#pragma unroll
        for (int ci = 0; ci < 6; ++ci)
            hwX[((size_t)b * 96 + tc * 6 + ci) * DD + i0 + tr * 4 + ri] = acc[ri][ci];
}

// ---------------------------------------------------------------------------
// K2: attn + masked log_softmax over text axis, written transposed:
//   logpT[b][j][i]
// ---------------------------------------------------------------------------
__global__ __launch_bounds__(256) void k2_attn(const float* __restrict__ hwX,
                                               const float* __restrict__ mel,
                                               const int* __restrict__ tlen,
                                               const int* __restrict__ mlen,
                                               float* __restrict__ logpT) {
    const int b = blockIdx.y;
    const int ml = mlen[b];
    const int j0 = blockIdx.x * 32;
    if (j0 >= ml) return;
    const int tl = tlen[b];
    const int tid = threadIdx.x;
    const int ig = tid >> 2;   // 64 i-groups, 8 rows each
    const int jg = tid & 3;    // 4 j-groups, 8 cols each

    __shared__ __align__(16) float hwS[16 * 512];
    __shared__ __align__(16) float melS[16 * 32];
    __shared__ float red[32 * 64];
    __shared__ float colmax[32];
    __shared__ float lsum[32];

    float acc[8][8];
#pragma unroll
    for (int a = 0; a < 8; ++a)
#pragma unroll
        for (int c = 0; c < 8; ++c) acc[a][c] = 0.f;

    for (int mc = 0; mc < 80; mc += 16) {
        __syncthreads();
#pragma unroll
        for (int p = 0; p < 8; ++p) {
            int lin = p * 256 + tid;            // 0..2047 float4s
            int mm = lin >> 7, iq = lin & 127;
            *(float4*)&hwS[mm * 512 + iq * 4] =
                *(const float4*)&hwX[((size_t)b * 96 + mc + mm) * DD + iq * 4];
        }
#pragma unroll
        for (int p = 0; p < 2; ++p) {
            int lin = p * 256 + tid;            // 0..511
            int mm = lin >> 5, jj = lin & 31;
            melS[lin] = mel[((size_t)b * 80 + mc + mm) * TM + j0 + jj];
        }
        __syncthreads();
#pragma unroll
        for (int mm = 0; mm < 16; ++mm) {
            float4 a0 = *(const float4*)&hwS[mm * 512 + ig * 8];
            float4 a1 = *(const float4*)&hwS[mm * 512 + ig * 8 + 4];
            float4 b0 = *(const float4*)&melS[mm * 32 + jg * 8];
            float4 b1 = *(const float4*)&melS[mm * 32 + jg * 8 + 4];
            float av[8] = {a0.x, a0.y, a0.z, a0.w, a1.x, a1.y, a1.z, a1.w};
            float bv[8] = {b0.x, b0.y, b0.z, b0.w, b1.x, b1.y, b1.z, b1.w};
#pragma unroll
            for (int ii = 0; ii < 8; ++ii)
#pragma unroll
                for (int jj = 0; jj < 8; ++jj) acc[ii][jj] += av[ii] * bv[jj];
        }
    }
    float4 h0 = *(const float4*)&hwX[((size_t)b * 96 + 80) * DD + ig * 8];
    float4 h1 = *(const float4*)&hwX[((size_t)b * 96 + 80) * DD + ig * 8 + 4];
    float hb[8] = {h0.x, h0.y, h0.z, h0.w, h1.x, h1.y, h1.z, h1.w};
#pragma unroll
    for (int ii = 0; ii < 8; ++ii) {
        bool valid = (ig * 8 + ii) < tl;
#pragma unroll
        for (int jj = 0; jj < 8; ++jj)
            acc[ii][jj] = valid ? (acc[ii][jj] + hb[ii]) : NEGF;
    }
    __syncthreads();
#pragma unroll
    for (int jj = 0; jj < 8; ++jj) {
        float m = acc[0][jj];
#pragma unroll
        for (int ii = 1; ii < 8; ++ii) m = fmaxf(m, acc[ii][jj]);
        red[(jg * 8 + jj) * 64 + ig] = m;
    }
    __syncthreads();
    if (tid < 32) {
        float m = red[tid * 64];
        for (int g = 1; g < 64; ++g) m = fmaxf(m, red[tid * 64 + g]);
        colmax[tid] = m;
    }
    __syncthreads();
#pragma unroll
    for (int jj = 0; jj < 8; ++jj) {
        float cm = colmax[jg * 8 + jj];
        float s = 0.f;
#pragma unroll
        for (int ii = 0; ii < 8; ++ii) s += expf(acc[ii][jj] - cm);
        red[(jg * 8 + jj) * 64 + ig] = s;
    }
    __syncthreads();
    if (tid < 32) {
        float s = 0.f;
        for (int g = 0; g < 64; ++g) s += red[tid * 64 + g];
        lsum[tid] = logf(s);
    }
    __syncthreads();
#pragma unroll
    for (int jj = 0; jj < 8; ++jj) {
        int j = j0 + jg * 8 + jj;
        if (j < ml) {
            float cm = colmax[jg * 8 + jj], ls = lsum[jg * 8 + jj];
            float o[8];
#pragma unroll
            for (int ii = 0; ii < 8; ++ii) {
                int i = ig * 8 + ii;
                o[ii] = (i < tl) ? ((acc[ii][jj] - cm) - ls) : NEGF;
            }
            float* dst = &logpT[((size_t)b * TM + j) * TT + ig * 8];
            *(float4*)dst = make_float4(o[0], o[1], o[2], o[3]);
            *(float4*)(dst + 4) = make_float4(o[4], o[5], o[6], o[7]);
        }
    }
}

// ---------------------------------------------------------------------------
// K3: MAS forward DP, r5 restructure: NO LDS staging at all. Each lane needs
// only its own 32B per column (rows 8l..8l+7), so logp columns are streamed
// directly into a triple-buffered register file (2x global_load_dwordx4 per
// column, 8-column batches, 3 statically-indexed buffers). Single wave, no
// barriers -> the compiler emits counted s_waitcnt vmcnt(N); effective
// prefetch distance ~16 columns (~2700 cyc of VALU) covers HBM-miss latency.
// Over-read tail columns (j>2047, incl. issue-ahead batches) land in the
// following batch's columns / hwX region: finite garbage, choice bits never
// flushed past word 63 and never read by backtrack (same argument as the old
// clamped-dummy tail).
// One wave per batch; lane l owns rows 8l..8l+7; DPP wave_shr:1 passes q[7].
// ---------------------------------------------------------------------------
#define BCOLS 8
#define NBATCH 258   // >= ceil(2047/8)=256, multiple of 3 for buffer rotation

// lane l gets src from lane l-1; lane 0 gets `old` (bound_ctrl=false).
__device__ __forceinline__ float dpp_shr1(float old, float src) {
    return __int_as_float(__builtin_amdgcn_update_dpp(
        __float_as_int(old), __float_as_int(src), 0x138, 0xF, 0xF, false));
}

__global__ __launch_bounds__(64, 1) void k3_dp(const float* __restrict__ logpT,
                                               const int* __restrict__ tlen,
                                               const int* __restrict__ mlen,
                                               unsigned* __restrict__ gwords,
                                               int* __restrict__ idxmap,
                                               float* __restrict__ dOut) {
    const int b = blockIdx.x;
    const int lane = threadIdx.x;
    const int tl = tlen[b];
    const int ml = mlen[b];
    __shared__ int durs[TT];
#pragma unroll
    for (int k = 0; k < 8; ++k) durs[lane * 8 + k] = 0;

    const float* colbase = logpT + (size_t)b * TM * TT;
    unsigned* gwb = gwords + (size_t)b * TT * 64;

    float q[8];
    unsigned accb[8];
#pragma unroll
    for (int k = 0; k < 8; ++k) { q[k] = NEGF; accb[k] = 0u; }
    if (lane == 0) q[0] = colbase[0];          // logp[b][j=0][i=0]

    unsigned* gp = gwb + lane * 8 * 64;        // flush cursor (word 0)
    int jj = 1;
    const float* lanebase = colbase + lane * 8;   // lane's 32B within a column

    // triple-buffered register file: 3 batches x 8 cols x 8 floats = 192 VGPR
    float4 ra0[BCOLS], rb0[BCOLS], ra1[BCOLS], rb1[BCOLS], ra2[BCOLS], rb2[BCOLS];

#define ISSUE(nb_, ra_, rb_) do {                                              \
        const float* g_ = lanebase + ((size_t)(1 + (nb_) * BCOLS)) * 512;      \
        _Pragma("unroll")                                                      \
        for (int p_ = 0; p_ < BCOLS; ++p_) {                                   \
            ra_[p_] = *(const float4*)(g_ + (size_t)p_ * 512);                 \
            rb_[p_] = *(const float4*)(g_ + (size_t)p_ * 512 + 4);             \
        }                                                                      \
    } while (0)

#define STEPS(ra_, rb_) do {                                                   \
        _Pragma("unroll")                                                      \
        for (int p_ = 0; p_ < BCOLS; ++p_) {                                   \
            float lp_[8] = {ra_[p_].x, ra_[p_].y, ra_[p_].z, ra_[p_].w,        \
                            rb_[p_].x, rb_[p_].y, rb_[p_].z, rb_[p_].w};       \
            float nb_[8];                                                      \
            nb_[0] = dpp_shr1(NEGF, q[7]);                                     \
            _Pragma("unroll")                                                  \
            for (int k_ = 1; k_ < 8; ++k_) nb_[k_] = q[k_ - 1];                \
            const unsigned m32_ = 1u << (jj & 31);                             \
            _Pragma("unroll")                                                  \
            for (int k_ = 0; k_ < 8; ++k_) {                                   \
                if (nb_[k_] > q[k_]) accb[k_] |= m32_;                         \
                q[k_] = lp_[k_] + fmaxf(q[k_], nb_[k_]);                       \
            }                                                                  \
            if ((jj & 31) == 31) {             /* word complete (uniform) */   \
                _Pragma("unroll")                                              \
                for (int k_ = 0; k_ < 8; ++k_) {                               \
                    gp[k_ * 64] = accb[k_]; accb[k_] = 0u;                     \
                }                                                              \
                gp += 1;                                                       \
            }                                                                  \
            ++jj;                                                              \
        }                                                                      \
    } while (0)

    ISSUE(0, ra0, rb0);
    ISSUE(1, ra1, rb1);
    for (int n = 0; n < NBATCH; n += 3) {
        ISSUE(n + 2, ra2, rb2);
        STEPS(ra0, rb0);
        ISSUE(n + 3, ra0, rb0);
        STEPS(ra1, rb1);
        ISSUE(n + 4, ra1, rb1);
        STEPS(ra2, rb2);
    }
#undef ISSUE
#undef STEPS

    __threadfence();
    __syncthreads();

    // ---- wave-parallel backtrack: lane = word index within a row ----
    {
        int i = tl - 1;
        int j = ml - 1;
        unsigned r0, r1, r2, r3, r4, r5, r6, r7;   // 8-deep row shift register
        {
            int a0 = tl - 1, a1 = tl - 2, a2 = tl - 3, a3 = tl - 4;
            int a4 = tl - 5, a5 = tl - 6, a6 = tl - 7, a7 = tl - 8;
            a1 = a1 < 0 ? 0 : a1; a2 = a2 < 0 ? 0 : a2; a3 = a3 < 0 ? 0 : a3;
            a4 = a4 < 0 ? 0 : a4; a5 = a5 < 0 ? 0 : a5; a6 = a6 < 0 ? 0 : a6;
            a7 = a7 < 0 ? 0 : a7;
            r0 = gwb[a0 * 64 + lane]; r1 = gwb[a1 * 64 + lane];
            r2 = gwb[a2 * 64 + lane]; r3 = gwb[a3 * 64 + lane];
            r4 = gwb[a4 * 64 + lane]; r5 = gwb[a5 * 64 + lane];
            r6 = gwb[a6 * 64 + lane]; r7 = gwb[a7 * 64 + lane];
        }
        int nf = tl - 9;
        int guard = TT + 2;
        while (guard-- > 0) {
            unsigned w = r0;
            r0 = r1; r1 = r2; r2 = r3; r3 = r4; r4 = r5; r5 = r6; r6 = r7;
            {
                int rf = (nf < 0) ? 0 : nf;
                r7 = gwb[rf * 64 + lane];
                --nf;
            }
            int jw = j >> 5, rr = j & 31;
            unsigned topmask = (rr == 31) ? 0xFFFFFFFFu : ((1u << (rr + 1)) - 1u);
            unsigned wm = (lane < jw) ? w : ((lane == jw) ? (w & topmask) : 0u);
            unsigned long long bal = __ballot(wm != 0u);
            if (bal == 0ull) {                 // no transition: row i covers 0..j
                if (lane == 0) durs[i] = j + 1;
                break;
            }
            int hl = 63 - __clzll(bal);        // highest lane (word) with a bit
            unsigned whl = (unsigned)__builtin_amdgcn_readlane((int)wm, hl);
            int jp = (hl << 5) + (31 - __clz(whl));   // largest set bit <= j
            if (lane == 0) durs[i] = j - jp + 1;
            j = jp - 1;
            if (--i < 0) break;
        }
    }
    __syncthreads();

    // ---- durations -> d_out; exclusive cumsum -> idxmap scatter fill ----
    int d[8], pre[8];
    int run = 0;
#pragma unroll
    for (int k = 0; k < 8; ++k) { d[k] = durs[lane * 8 + k]; pre[k] = run; run += d[k]; }
    int v = run;
#pragma unroll
    for (int off = 1; off < 64; off <<= 1) {
        int n = __shfl_up(v, off);
        if (lane >= off) v += n;
    }
    int base = v - run;
#pragma unroll
    for (int k = 0; k < 8; ++k) {
        int i = lane * 8 + k;
        dOut[DUR_OFF + (size_t)b * TT + i] = (float)d[k];
        int st = base + pre[k];
        for (int t2 = 0; t2 < d[k]; ++t2) idxmap[b * TM + st + t2] = i;
    }
}

// ---------------------------------------------------------------------------
// K4: length-regulate expansion. One block per output row (b, j).
// ---------------------------------------------------------------------------
__global__ __launch_bounds__(128) void k4_expand(const float* __restrict__ h_text,
                                                 const int* __restrict__ idxmap,
                                                 const int* __restrict__ mlen,
                                                 float* __restrict__ dOut) {
    int bid = blockIdx.x;
    int b = bid >> 11;
    int j = bid & (TM - 1);
    int t = threadIdx.x;
    float4* orow = (float4*)dOut + (size_t)bid * 128;
    if (j < mlen[b]) {
        int i = idxmap[bid];
        const float4* hrow = (const float4*)h_text + ((size_t)(b * TT + i)) * 128;
        orow[t] = hrow[t];
    } else {
        orow[t] = make_float4(0.f, 0.f, 0.f, 0.f);
    }
}

// ---------------------------------------------------------------------------
// K5: masked sum-MSE duration loss
// ---------------------------------------------------------------------------
__global__ __launch_bounds__(256) void k5_loss(const float* __restrict__ pred,
                                               const int* __restrict__ tlen,
                                               float* __restrict__ dOut) {
    __shared__ float rs[256];
    __shared__ int rc[256];
    int t = threadIdx.x;
    float s = 0.f;
    int c = 0;
    for (int idx = t; idx < Bn * TT; idx += 256) {
        int b = idx >> 9, i = idx & 511;
        if (i < tlen[b]) {
            float dv = dOut[DUR_OFF + idx];
            float lg = logf(fmaxf(dv, 1.0f));
            float df = pred[idx] - lg;
            s += df * df;
            c += 1;
        }
    }
    rs[t] = s; rc[t] = c;
    __syncthreads();
    for (int off = 128; off > 0; off >>= 1) {
        if (t < off) { rs[t] += rs[t + off]; rc[t] += rc[t + off]; }
        __syncthreads();
    }
    if (t == 0) dOut[LOSS_OFF] = rs[0] / (float)rc[0];
}

// ---------------------------------------------------------------------------
extern "C" void kernel_launch(void* const* d_in, const int* in_sizes, int n_in,
                              void* d_out, int out_size, void* d_ws, size_t ws_size,
                              hipStream_t stream) {
    const float* h_text = (const float*)d_in[0];
    const float* mel    = (const float*)d_in[1];
    const int*   tlen   = (const int*)d_in[2];
    const int*   mlen   = (const int*)d_in[3];
    const float* w      = (const float*)d_in[4];
    const float* bias   = (const float*)d_in[5];
    const float* pred   = (const float*)d_in[6];
    float* out = (float*)d_out;

    // workspace carve-up (~138.5 MB)
    float*    logpT  = (float*)d_ws;                              // 32*2048*512 f32 (128 MB)
    float*    hwX    = logpT + (size_t)Bn * TM * TT;              // 32*96*512 f32 (also k3's over-read slack)
    float*    wTx    = hwX + (size_t)Bn * 96 * DD;                // 96*512 f32
    unsigned* gwords = (unsigned*)(wTx + 96 * DD);                // 32*512*64 u32 (4 MB)
    int*      idxmap = (int*)(gwords + (size_t)Bn * TT * 64);     // 32*2048 i32

    k0_wtx<<<dim3(96), dim3(256), 0, stream>>>(w, bias, wTx);
    k1_hw<<<dim3(256), dim3(256), 0, stream>>>(h_text, wTx, hwX);
    k2_attn<<<dim3(64, 32), dim3(256), 0, stream>>>(hwX, mel, tlen, mlen, logpT);
    k3_dp<<<dim3(32), dim3(64), 0, stream>>>(logpT, tlen, mlen, gwords, idxmap, out);
    k4_expand<<<dim3(Bn * TM), dim3(128), 0, stream>>>(h_text, idxmap, mlen, out);
    k5_loss<<<dim3(1), dim3(256), 0, stream>>>(pred, tlen, out);
}

// Round 4
// 727.581 us; speedup vs baseline: 1.1379x; 1.0344x over previous
//
#include <hip/hip_runtime.h>
#include <math.h>

// Problem constants (fixed shapes from setup_inputs)
#define Bn 32
#define TT 512
#define TM 2048
#define DD 512
#define MMp 80
#define NEGF (-1.0e9f)

// d_out layout: [h_expanded 32*2048*512][dur_loss 1][durations 32*512], all float32
constexpr size_t LOSS_OFF = (size_t)Bn * TM * DD;          // 33554432
constexpr size_t DUR_OFF  = LOSS_OFF + 1;                  // 33554433

// ---------------------------------------------------------------------------
// K0: build wTx[96][512]: rows 0..79 = w_proj^T, row 80 = b_proj, 81..95 = 0
// ---------------------------------------------------------------------------
__global__ __launch_bounds__(256) void k0_wtx(const float* __restrict__ w,
                                              const float* __restrict__ bias,
                                              float* __restrict__ wTx) {
    int m = blockIdx.x;
    for (int d = threadIdx.x; d < DD; d += 256) {
        float v = 0.f;
        if (m < 80) v = w[d * 80 + m];
        else if (m == 80) v = bias[d];
        wTx[m * DD + d] = v;
    }
}

// ---------------------------------------------------------------------------
// K1: hwX[b][m][i] = sum_d h_text[b][i][d] * wTx[m][d]   (m<96, row80 = h.b)
// ---------------------------------------------------------------------------
__global__ __launch_bounds__(256) void k1_hw(const float* __restrict__ h_text,
                                             const float* __restrict__ wTx,
                                             float* __restrict__ hwX) {
    int bid = blockIdx.x;
    int b = bid >> 3;
    int i0 = (bid & 7) * 64;
    int t = threadIdx.x;
    int tr = t & 15, tc = t >> 4;
    __shared__ __align__(16) float Asub[64 * 68];
    __shared__ __align__(16) float Bsub[96 * 68];
    float acc[4][6];
#pragma unroll
    for (int a = 0; a < 4; ++a)
#pragma unroll
        for (int c = 0; c < 6; ++c) acc[a][c] = 0.f;

    for (int d0 = 0; d0 < DD; d0 += 64) {
        __syncthreads();
#pragma unroll
        for (int p = 0; p < 4; ++p) {
            int lin = p * 256 + t;              // 0..1023
            int r = lin >> 4, dq = lin & 15;
            *(float4*)&Asub[r * 68 + dq * 4] =
                *(const float4*)&h_text[((size_t)(b * TT + i0 + r)) * DD + d0 + dq * 4];
        }
#pragma unroll
        for (int p = 0; p < 6; ++p) {
            int lin = p * 256 + t;              // 0..1535
            int cc = lin >> 4, dq = lin & 15;
            *(float4*)&Bsub[cc * 68 + dq * 4] =
                *(const float4*)&wTx[(size_t)cc * DD + d0 + dq * 4];
        }
        __syncthreads();
#pragma unroll
        for (int dd = 0; dd < 16; ++dd) {
            float4 a[4], bb[6];
#pragma unroll
            for (int ri = 0; ri < 4; ++ri)
                a[ri] = *(const float4*)&Asub[(tr * 4 + ri) * 68 + dd * 4];
#pragma unroll
            for (int ci = 0; ci < 6; ++ci)
                bb[ci] = *(const float4*)&Bsub[(tc * 6 + ci) * 68 + dd * 4];
#pragma unroll
            for (int ri = 0; ri < 4; ++ri)
#pragma unroll
                for (int ci = 0; ci < 6; ++ci) {
                    acc[ri][ci] += a[ri].x * bb[ci].x;
                    acc[ri][ci] += a[ri].y * bb[ci].y;
                    acc[ri][ci] += a[ri].z * bb[ci].z;
                    acc[ri][ci] += a[ri].w * bb[ci].w;
                }
        }
    }
#pragma unroll
    for (int ri = 0; ri < 4; ++ri)
#pragma unroll
        for (int ci = 0; ci < 6; ++ci)
            hwX[((size_t)b * 96 + tc * 6 + ci) * DD + i0 + tr * 4 + ri] = acc[ri][ci];
}

// ---------------------------------------------------------------------------
// K2: attn + masked log_softmax over text axis, written transposed:
//   logpT[b][j][i]
// ---------------------------------------------------------------------------
__global__ __launch_bounds__(256) void k2_attn(const float* __restrict__ hwX,
                                               const float* __restrict__ mel,
                                               const int* __restrict__ tlen,
                                               const int* __restrict__ mlen,
                                               float* __restrict__ logpT) {
    const int b = blockIdx.y;
    const int ml = mlen[b];
    const int j0 = blockIdx.x * 32;
    if (j0 >= ml) return;
    const int tl = tlen[b];
    const int tid = threadIdx.x;
    const int ig = tid >> 2;   // 64 i-groups, 8 rows each
    const int jg = tid & 3;    // 4 j-groups, 8 cols each

    __shared__ __align__(16) float hwS[16 * 512];
    __shared__ __align__(16) float melS[16 * 32];
    __shared__ float red[32 * 64];
    __shared__ float colmax[32];
    __shared__ float lsum[32];

    float acc[8][8];
#pragma unroll
    for (int a = 0; a < 8; ++a)
#pragma unroll
        for (int c = 0; c < 8; ++c) acc[a][c] = 0.f;

    for (int mc = 0; mc < 80; mc += 16) {
        __syncthreads();
#pragma unroll
        for (int p = 0; p < 8; ++p) {
            int lin = p * 256 + tid;            // 0..2047 float4s
            int mm = lin >> 7, iq = lin & 127;
            *(float4*)&hwS[mm * 512 + iq * 4] =
                *(const float4*)&hwX[((size_t)b * 96 + mc + mm) * DD + iq * 4];
        }
#pragma unroll
        for (int p = 0; p < 2; ++p) {
            int lin = p * 256 + tid;            // 0..511
            int mm = lin >> 5, jj = lin & 31;
            melS[lin] = mel[((size_t)b * 80 + mc + mm) * TM + j0 + jj];
        }
        __syncthreads();
#pragma unroll
        for (int mm = 0; mm < 16; ++mm) {
            float4 a0 = *(const float4*)&hwS[mm * 512 + ig * 8];
            float4 a1 = *(const float4*)&hwS[mm * 512 + ig * 8 + 4];
            float4 b0 = *(const float4*)&melS[mm * 32 + jg * 8];
            float4 b1 = *(const float4*)&melS[mm * 32 + jg * 8 + 4];
            float av[8] = {a0.x, a0.y, a0.z, a0.w, a1.x, a1.y, a1.z, a1.w};
            float bv[8] = {b0.x, b0.y, b0.z, b0.w, b1.x, b1.y, b1.z, b1.w};
#pragma unroll
            for (int ii = 0; ii < 8; ++ii)
#pragma unroll
                for (int jj = 0; jj < 8; ++jj) acc[ii][jj] += av[ii] * bv[jj];
        }
    }
    float4 h0 = *(const float4*)&hwX[((size_t)b * 96 + 80) * DD + ig * 8];
    float4 h1 = *(const float4*)&hwX[((size_t)b * 96 + 80) * DD + ig * 8 + 4];
    float hb[8] = {h0.x, h0.y, h0.z, h0.w, h1.x, h1.y, h1.z, h1.w};
#pragma unroll
    for (int ii = 0; ii < 8; ++ii) {
        bool valid = (ig * 8 + ii) < tl;
#pragma unroll
        for (int jj = 0; jj < 8; ++jj)
            acc[ii][jj] = valid ? (acc[ii][jj] + hb[ii]) : NEGF;
    }
    __syncthreads();
#pragma unroll
    for (int jj = 0; jj < 8; ++jj) {
        float m = acc[0][jj];
#pragma unroll
        for (int ii = 1; ii < 8; ++ii) m = fmaxf(m, acc[ii][jj]);
        red[(jg * 8 + jj) * 64 + ig] = m;
    }
    __syncthreads();
    if (tid < 32) {
        float m = red[tid * 64];
        for (int g = 1; g < 64; ++g) m = fmaxf(m, red[tid * 64 + g]);
        colmax[tid] = m;
    }
    __syncthreads();
#pragma unroll
    for (int jj = 0; jj < 8; ++jj) {
        float cm = colmax[jg * 8 + jj];
        float s = 0.f;
#pragma unroll
        for (int ii = 0; ii < 8; ++ii) s += expf(acc[ii][jj] - cm);
        red[(jg * 8 + jj) * 64 + ig] = s;
    }
    __syncthreads();
    if (tid < 32) {
        float s = 0.f;
        for (int g = 0; g < 64; ++g) s += red[tid * 64 + g];
        lsum[tid] = logf(s);
    }
    __syncthreads();
#pragma unroll
    for (int jj = 0; jj < 8; ++jj) {
        int j = j0 + jg * 8 + jj;
        if (j < ml) {
            float cm = colmax[jg * 8 + jj], ls = lsum[jg * 8 + jj];
            float o[8];
#pragma unroll
            for (int ii = 0; ii < 8; ++ii) {
                int i = ig * 8 + ii;
                o[ii] = (i < tl) ? ((acc[ii][jj] - cm) - ls) : NEGF;
            }
            float* dst = &logpT[((size_t)b * TM + j) * TT + ig * 8];
            *(float4*)dst = make_float4(o[0], o[1], o[2], o[3]);
            *(float4*)(dst + 4) = make_float4(o[4], o[5], o[6], o[7]);
        }
    }
}

// ---------------------------------------------------------------------------
// K3: MAS forward DP, r8. The r6/r7 asm-load pipelines crashed (register-only
// RA copies of asm-load destinations are not ordered by a "memory"-clobber
// waitcnt — rule-#18 family; corrupted DP -> unbounded scatter-fill -> OOB
// past workspace end). r8 abandons asm loads entirely:
//   - PLAIN float4 loads (compiler owns s_waitcnt insertion -> correctness
//     guaranteed; it emits counted vmcnt(16) since it models its own loads)
//   - sched_barrier(0) fences pin region order so the RP scheduler cannot
//     sink batch n+2's loads down to their use (the r5 failure mode)
//   - double buffer: 2 x 8 cols x 8 floats = 128 load VGPRs, ~190 total,
//     spill-free at __launch_bounds__(64,1) (512-VGPR budget)
// Over-read tail (cols 2048..2064) lands in the hwX region: finite garbage,
// never flushed to gwords, never read by backtrack. Scatter-fill clamped to
// TM so any DP corruption becomes an absmax diagnosis, never an abort.
// One wave per batch; lane l owns rows 8l..8l+7; DPP wave_shr:1 passes q[7].
// ---------------------------------------------------------------------------
#define BCOLS 8
#define NBATCH 256   // columns processed: 1..2048 (2047 real + 1 slack)

typedef float vf4 __attribute__((ext_vector_type(4)));

#define SB0() __builtin_amdgcn_sched_barrier(0)

// lane l gets src from lane l-1; lane 0 gets `old` (bound_ctrl=false).
__device__ __forceinline__ float dpp_shr1(float old, float src) {
    return __int_as_float(__builtin_amdgcn_update_dpp(
        __float_as_int(old), __float_as_int(src), 0x138, 0xF, 0xF, false));
}

__global__ __launch_bounds__(64, 1) void k3_dp(const float* __restrict__ logpT,
                                               const int* __restrict__ tlen,
                                               const int* __restrict__ mlen,
                                               unsigned* __restrict__ gwords,
                                               int* __restrict__ idxmap,
                                               float* __restrict__ dOut) {
    const int b = blockIdx.x;
    const int lane = threadIdx.x;
    const int tl = tlen[b];
    const int ml = mlen[b];
    __shared__ int durs[TT];
#pragma unroll
    for (int k = 0; k < 8; ++k) durs[lane * 8 + k] = 0;

    const float* colbase = logpT + (size_t)b * TM * TT;
    unsigned* gwb = gwords + (size_t)b * TT * 64;

    float q[8];
    unsigned accb[8];
#pragma unroll
    for (int k = 0; k < 8; ++k) { q[k] = NEGF; accb[k] = 0u; }
    if (lane == 0) q[0] = colbase[0];          // logp[b][j=0][i=0]

    unsigned* gp = gwb + lane * 8 * 64;        // flush cursor (word 0)
    int jj = 1;
    const float* lanebase = colbase + lane * 8;   // lane's 32B within a column

    // double-buffered register file: 2 batches x 8 cols x 8 floats = 128 VGPR
    vf4 ra0[BCOLS], rb0[BCOLS], ra1[BCOLS], rb1[BCOLS];

#define ISSUE(nb_, ra_, rb_) do {                                              \
        const float* g_ = lanebase + ((size_t)(1 + (nb_) * 8)) * 512;          \
        _Pragma("unroll")                                                      \
        for (int p_ = 0; p_ < BCOLS; ++p_) {                                   \
            ra_[p_] = *(const vf4*)(g_ + (size_t)p_ * 512);                    \
            rb_[p_] = *(const vf4*)(g_ + (size_t)p_ * 512 + 4);                \
        }                                                                      \
    } while (0)

#define STEPS(ra_, rb_) do {                                                   \
        _Pragma("unroll")                                                      \
        for (int p_ = 0; p_ < BCOLS; ++p_) {                                   \
            float lp_[8] = {ra_[p_][0], ra_[p_][1], ra_[p_][2], ra_[p_][3],    \
                            rb_[p_][0], rb_[p_][1], rb_[p_][2], rb_[p_][3]};   \
            float nb_[8];                                                      \
            nb_[0] = dpp_shr1(NEGF, q[7]);                                     \
            _Pragma("unroll")                                                  \
            for (int k_ = 1; k_ < 8; ++k_) nb_[k_] = q[k_ - 1];                \
            const unsigned m32_ = 1u << (jj & 31);                             \
            _Pragma("unroll")                                                  \
            for (int k_ = 0; k_ < 8; ++k_) {                                   \
                if (nb_[k_] > q[k_]) accb[k_] |= m32_;                         \
                q[k_] = lp_[k_] + fmaxf(q[k_], nb_[k_]);                       \
            }                                                                  \
            if ((jj & 31) == 31) {             /* word complete (uniform) */   \
                _Pragma("unroll")                                              \
                for (int k_ = 0; k_ < 8; ++k_) {                               \
                    gp[k_ * 64] = accb[k_]; accb[k_] = 0u;                     \
                }                                                              \
                gp += 1;                                                       \
            }                                                                  \
            ++jj;                                                              \
        }                                                                      \
    } while (0)

    ISSUE(0, ra0, rb0);
    ISSUE(1, ra1, rb1);
    for (int n = 0; n < NBATCH; n += 2) {
        SB0();
        STEPS(ra0, rb0);                        // compiler: vmcnt(16) wait
        SB0();
        ISSUE(n + 2, ra0, rb0);
        SB0();
        STEPS(ra1, rb1);
        SB0();
        ISSUE(n + 3, ra1, rb1);
    }
    SB0();
#undef ISSUE
#undef STEPS

    __threadfence();
    __syncthreads();

    // ---- wave-parallel backtrack: lane = word index within a row ----
    {
        int i = tl - 1;
        int j = ml - 1;
        unsigned r0, r1, r2, r3, r4, r5, r6, r7;   // 8-deep row shift register
        {
            int a0 = tl - 1, a1 = tl - 2, a2 = tl - 3, a3 = tl - 4;
            int a4 = tl - 5, a5 = tl - 6, a6 = tl - 7, a7 = tl - 8;
            a1 = a1 < 0 ? 0 : a1; a2 = a2 < 0 ? 0 : a2; a3 = a3 < 0 ? 0 : a3;
            a4 = a4 < 0 ? 0 : a4; a5 = a5 < 0 ? 0 : a5; a6 = a6 < 0 ? 0 : a6;
            a7 = a7 < 0 ? 0 : a7;
            r0 = gwb[a0 * 64 + lane]; r1 = gwb[a1 * 64 + lane];
            r2 = gwb[a2 * 64 + lane]; r3 = gwb[a3 * 64 + lane];
            r4 = gwb[a4 * 64 + lane]; r5 = gwb[a5 * 64 + lane];
            r6 = gwb[a6 * 64 + lane]; r7 = gwb[a7 * 64 + lane];
        }
        int nf = tl - 9;
        int guard = TT + 2;
        while (guard-- > 0) {
            unsigned w = r0;
            r0 = r1; r1 = r2; r2 = r3; r3 = r4; r4 = r5; r5 = r6; r6 = r7;
            {
                int rf = (nf < 0) ? 0 : nf;
                r7 = gwb[rf * 64 + lane];
                --nf;
            }
            int jw = j >> 5, rr = j & 31;
            unsigned topmask = (rr == 31) ? 0xFFFFFFFFu : ((1u << (rr + 1)) - 1u);
            unsigned wm = (lane < jw) ? w : ((lane == jw) ? (w & topmask) : 0u);
            unsigned long long bal = __ballot(wm != 0u);
            if (bal == 0ull) {                 // no transition: row i covers 0..j
                if (lane == 0) durs[i] = j + 1;
                break;
            }
            int hl = 63 - __clzll(bal);        // highest lane (word) with a bit
            unsigned whl = (unsigned)__builtin_amdgcn_readlane((int)wm, hl);
            int jp = (hl << 5) + (31 - __clz(whl));   // largest set bit <= j
            if (lane == 0) durs[i] = j - jp + 1;
            j = jp - 1;
            if (--i < 0) break;
        }
    }
    __syncthreads();

    // ---- durations -> d_out; exclusive cumsum -> idxmap scatter fill ----
    // Scatter clamped to TM: DP corruption shows as absmax, never OOB/abort.
    int d[8], pre[8];
    int run = 0;
#pragma unroll
    for (int k = 0; k < 8; ++k) { d[k] = durs[lane * 8 + k]; pre[k] = run; run += d[k]; }
    int v = run;
#pragma unroll
    for (int off = 1; off < 64; off <<= 1) {
        int n = __shfl_up(v, off);
        if (lane >= off) v += n;
    }
    int base = v - run;
#pragma unroll
    for (int k = 0; k < 8; ++k) {
        int i = lane * 8 + k;
        dOut[DUR_OFF + (size_t)b * TT + i] = (float)d[k];
        int st = base + pre[k];
        int en = st + d[k];
        if (en > TM) en = TM;
        if (st < 0) st = 0;
        for (int t2 = st; t2 < en; ++t2) idxmap[b * TM + t2] = i;
    }
}

// ---------------------------------------------------------------------------
// K4: length-regulate expansion. One block per output row (b, j).
// Index clamped to [0,511]: any upstream DP corruption becomes a diagnosable
// absmax failure instead of an OOB read -> SIGABRT with no counters.
// ---------------------------------------------------------------------------
__global__ __launch_bounds__(128) void k4_expand(const float* __restrict__ h_text,
                                                 const int* __restrict__ idxmap,
                                                 const int* __restrict__ mlen,
                                                 float* __restrict__ dOut) {
    int bid = blockIdx.x;
    int b = bid >> 11;
    int j = bid & (TM - 1);
    int t = threadIdx.x;
    float4* orow = (float4*)dOut + (size_t)bid * 128;
    if (j < mlen[b]) {
        int i = idxmap[bid] & (TT - 1);
        const float4* hrow = (const float4*)h_text + ((size_t)(b * TT + i)) * 128;
        orow[t] = hrow[t];
    } else {
        orow[t] = make_float4(0.f, 0.f, 0.f, 0.f);
    }
}

// ---------------------------------------------------------------------------
// K5: masked sum-MSE duration loss
// ---------------------------------------------------------------------------
__global__ __launch_bounds__(256) void k5_loss(const float* __restrict__ pred,
                                               const int* __restrict__ tlen,
                                               float* __restrict__ dOut) {
    __shared__ float rs[256];
    __shared__ int rc[256];
    int t = threadIdx.x;
    float s = 0.f;
    int c = 0;
    for (int idx = t; idx < Bn * TT; idx += 256) {
        int b = idx >> 9, i = idx & 511;
        if (i < tlen[b]) {
            float dv = dOut[DUR_OFF + idx];
            float lg = logf(fmaxf(dv, 1.0f));
            float df = pred[idx] - lg;
            s += df * df;
            c += 1;
        }
    }
    rs[t] = s; rc[t] = c;
    __syncthreads();
    for (int off = 128; off > 0; off >>= 1) {
        if (t < off) { rs[t] += rs[t + off]; rc[t] += rc[t + off]; }
        __syncthreads();
    }
    if (t == 0) dOut[LOSS_OFF] = rs[0] / (float)rc[0];
}

// ---------------------------------------------------------------------------
extern "C" void kernel_launch(void* const* d_in, const int* in_sizes, int n_in,
                              void* d_out, int out_size, void* d_ws, size_t ws_size,
                              hipStream_t stream) {
    const float* h_text = (const float*)d_in[0];
    const float* mel    = (const float*)d_in[1];
    const int*   tlen   = (const int*)d_in[2];
    const int*   mlen   = (const int*)d_in[3];
    const float* w      = (const float*)d_in[4];
    const float* bias   = (const float*)d_in[5];
    const float* pred   = (const float*)d_in[6];
    float* out = (float*)d_out;

    // workspace carve-up (~138.5 MB)
    float*    logpT  = (float*)d_ws;                              // 32*2048*512 f32 (128 MB)
    float*    hwX    = logpT + (size_t)Bn * TM * TT;              // 32*96*512 f32 (also k3's over-read slack)
    float*    wTx    = hwX + (size_t)Bn * 96 * DD;                // 96*512 f32
    unsigned* gwords = (unsigned*)(wTx + 96 * DD);                // 32*512*64 u32 (4 MB)
    int*      idxmap = (int*)(gwords + (size_t)Bn * TT * 64);     // 32*2048 i32

    k0_wtx<<<dim3(96), dim3(256), 0, stream>>>(w, bias, wTx);
    k1_hw<<<dim3(256), dim3(256), 0, stream>>>(h_text, wTx, hwX);
    k2_attn<<<dim3(64, 32), dim3(256), 0, stream>>>(hwX, mel, tlen, mlen, logpT);
    k3_dp<<<dim3(32), dim3(64), 0, stream>>>(logpT, tlen, mlen, gwords, idxmap, out);
    k4_expand<<<dim3(Bn * TM), dim3(128), 0, stream>>>(h_text, idxmap, mlen, out);
    k5_loss<<<dim3(1), dim3(256), 0, stream>>>(pred, tlen, out);
}